// Round 1
// baseline (491.676 us; speedup 1.0000x reference)
//
#include <hip/hip_runtime.h>
#include <hip/hip_bf16.h>

#define D 1024
#define WAVES_PER_BLOCK 4

__global__ __launch_bounds__(256) void CosineSimilarity_76785425318088_kernel(
    const float* __restrict__ premise,
    const float* __restrict__ hypothesis,
    float* __restrict__ out,
    int n_rows) {
    const int wave = threadIdx.x >> 6;       // wave index within block (wave = 64 lanes)
    const int lane = threadIdx.x & 63;
    const int row = blockIdx.x * WAVES_PER_BLOCK + wave;
    if (row >= n_rows) return;

    const float4* __restrict__ prow = reinterpret_cast<const float4*>(premise    + (size_t)row * D);
    const float4* __restrict__ hrow = reinterpret_cast<const float4*>(hypothesis + (size_t)row * D);

    float dot = 0.f, pp = 0.f, hh = 0.f;
    // D/4 = 256 float4 per row; 64 lanes -> 4 coalesced iterations.
    #pragma unroll
    for (int j = 0; j < D / 4 / 64; ++j) {
        float4 a = prow[j * 64 + lane];
        float4 b = hrow[j * 64 + lane];
        dot = fmaf(a.x, b.x, dot); dot = fmaf(a.y, b.y, dot);
        dot = fmaf(a.z, b.z, dot); dot = fmaf(a.w, b.w, dot);
        pp  = fmaf(a.x, a.x, pp);  pp  = fmaf(a.y, a.y, pp);
        pp  = fmaf(a.z, a.z, pp);  pp  = fmaf(a.w, a.w, pp);
        hh  = fmaf(b.x, b.x, hh);  hh  = fmaf(b.y, b.y, hh);
        hh  = fmaf(b.z, b.z, hh);  hh  = fmaf(b.w, b.w, hh);
    }

    // Wave-64 reduction (CDNA wavefront = 64 lanes, not 32).
    #pragma unroll
    for (int off = 32; off > 0; off >>= 1) {
        dot += __shfl_down(dot, off, 64);
        pp  += __shfl_down(pp,  off, 64);
        hh  += __shfl_down(hh,  off, 64);
    }

    if (lane == 0) {
        const float eps = 1e-12f;
        float denom = fmaxf(sqrtf(pp), eps) * fmaxf(sqrtf(hh), eps);
        out[row] = dot / denom;
    }
}

extern "C" void kernel_launch(void* const* d_in, const int* in_sizes, int n_in,
                              void* d_out, int out_size, void* d_ws, size_t ws_size,
                              hipStream_t stream) {
    const float* premise    = (const float*)d_in[0];
    const float* hypothesis = (const float*)d_in[1];
    float* out = (float*)d_out;
    const int n_rows = out_size;  // 65536

    const int blocks = (n_rows + WAVES_PER_BLOCK - 1) / WAVES_PER_BLOCK;
    CosineSimilarity_76785425318088_kernel<<<blocks, 256, 0, stream>>>(
        premise, hypothesis, out, n_rows);
}